// Round 8
// baseline (501.230 us; speedup 1.0000x reference)
//
#include <hip/hip_runtime.h>
#include <cstdint>
#include <cstddef>

#define NH 16
#define DH 64
#define SEQ 2048
#define DM 1024

typedef __attribute__((ext_vector_type(8))) short short8;
typedef __attribute__((ext_vector_type(4))) float f32x4;

__device__ __forceinline__ unsigned short f2bf(float f) {
  unsigned u = __builtin_bit_cast(unsigned, f);
  u += 0x7fffu + ((u >> 16) & 1u);
  return (unsigned short)(u >> 16);
}

__device__ __forceinline__ void gld_lds16(const void* g, void* l) {
  __builtin_amdgcn_global_load_lds((const __attribute__((address_space(1))) void*)g,
                                   (__attribute__((address_space(3))) void*)l,
                                   16, 0, 0);
}

// software grid barrier: release-flush on arrive, acquire-inv on observe.
// Safe because grid(512) x LDS(67.6KB) x launch_bounds(512,4) => exactly
// 2 blocks/CU, all 512 co-resident on 256 CUs.
__device__ __forceinline__ void grid_bar(unsigned* cnt, unsigned target) {
  __syncthreads();
  if (threadIdx.x == 0) {
    __hip_atomic_fetch_add(cnt, 1u, __ATOMIC_ACQ_REL, __HIP_MEMORY_SCOPE_AGENT);
    while (__hip_atomic_load(cnt, __ATOMIC_ACQUIRE, __HIP_MEMORY_SCOPE_AGENT) < target)
      __builtin_amdgcn_s_sleep(8);
  }
  __syncthreads();
}

// ==================== fused mega-kernel ====================
__global__ __launch_bounds__(512, 4) void fused_mha(
    const float* __restrict__ x, const float* __restrict__ wq,
    const float* __restrict__ wk, const float* __restrict__ wv,
    const float* __restrict__ wo,
    unsigned short* __restrict__ xb, unsigned short* __restrict__ wqkvb,
    unsigned short* __restrict__ wob, unsigned short* __restrict__ qb,
    unsigned short* __restrict__ kb, unsigned short* __restrict__ vtb,
    unsigned short* __restrict__ aob, float* __restrict__ dout,
    unsigned* __restrict__ bars) {
  __shared__ __align__(16) unsigned short smem[33792];  // 67584 B
  const int t = threadIdx.x;
  const int bid = blockIdx.x;
  const int lane = t & 63;
  const int wave = t >> 6;
  const int quad = (lane >> 4) & 3;
  const int l16 = lane & 15;
  const unsigned nblk = gridDim.x;

  // ---------------- P0: fp32 -> bf16 cast of x + 4 weights ----------------
  {
    const int gtid = bid * 512 + t;
#pragma unroll 1
    for (int it = 0; it < 12; ++it) {
      const int idx = it * 262144 + gtid;  // 3,145,728 float4 units
      if (idx < 2097152) {
        const float4 v = ((const float4*)x)[idx];
        ushort4 o;
        o.x = f2bf(v.x); o.y = f2bf(v.y); o.z = f2bf(v.z); o.w = f2bf(v.w);
        ((ushort4*)xb)[idx] = o;
      } else {
        const int widx = idx - 2097152;
        const int w = widx >> 18;
        const int off = widx & 262143;
        const float4* src =
            (const float4*)(w == 0 ? wq : w == 1 ? wk : w == 2 ? wv : wo);
        ushort4* dst = (w < 3) ? ((ushort4*)wqkvb + (size_t)w * 262144)
                               : (ushort4*)wob;
        const float4 v = src[off];
        ushort4 o;
        o.x = f2bf(v.x); o.y = f2bf(v.y); o.z = f2bf(v.z); o.w = f2bf(v.w);
        dst[off] = o;
      }
    }
  }
  grid_bar(bars + 0, nblk);

  // ---------------- P1: QKV GEMM, 3 x (128x128, BK=32) tiles ----------------
  {
    unsigned short* As = smem;          // 128*32
    unsigned short* Bs = smem + 4096;
    const int wm = (wave >> 2) * 64;    // 8 waves: 2(m) x 4(n) of 64x32
    const int wn = (wave & 3) * 32;
    const int srow = t >> 2;                       // 0..127
    const int sc = (t & 3) ^ ((srow >> 1) & 3);
    const int swz = (l16 >> 1) & 3;
#pragma unroll 1
    for (int tl = 0; tl < 3; ++tl) {
      const int tid = tl * 512 + bid;              // 0..1535
      const int bm = (tid / 24) * 128;
      const int bnf = (tid % 24) * 128;
      const int sel = bnf >> 10;                   // 0=Q 1=K 2=V
      const int bnl = bnf & 1023;
      const unsigned short* Ag = xb + (size_t)(bm + srow) * DM + sc * 8;
      const unsigned short* Bg = wqkvb + (size_t)(bnf + srow) * DM + sc * 8;

      f32x4 acc[4][2];
#pragma unroll
      for (int i = 0; i < 4; ++i)
#pragma unroll
        for (int j = 0; j < 2; ++j) acc[i][j] = {0.0f, 0.0f, 0.0f, 0.0f};

      for (int k0 = 0; k0 < DM; k0 += 32) {
        __syncthreads();
        gld_lds16(Ag + k0, As + t * 8);
        gld_lds16(Bg + k0, Bs + t * 8);
        __syncthreads();
        short8 af[4], bfr[2];
#pragma unroll
        for (int i = 0; i < 4; ++i)
          af[i] = *(const short8*)(As + (wm + i * 16 + l16) * 32 + ((quad ^ swz) * 8));
#pragma unroll
        for (int j = 0; j < 2; ++j)
          bfr[j] = *(const short8*)(Bs + (wn + j * 16 + l16) * 32 + ((quad ^ swz) * 8));
#pragma unroll
        for (int i = 0; i < 4; ++i)
#pragma unroll
          for (int j = 0; j < 2; ++j)
            acc[i][j] = __builtin_amdgcn_mfma_f32_16x16x32_bf16(af[i], bfr[j], acc[i][j], 0, 0, 0);
      }

#pragma unroll
      for (int i = 0; i < 4; ++i) {
#pragma unroll
        for (int j = 0; j < 2; ++j) {
#pragma unroll
          for (int r = 0; r < 4; ++r) {
            const int m = bm + wm + i * 16 + quad * 4 + r;
            const int n = bnl + wn + j * 16 + l16;
            const float v = acc[i][j][r];
            if (sel == 0) {
              qb[(size_t)m * DM + n] = f2bf(v * 0.125f);
            } else if (sel == 1) {
              kb[(size_t)m * DM + n] = f2bf(v);
            } else {
              const int bb = m >> 11, s = m & 2047;
              const int hh = n >> 6, d = n & 63;
              vtb[((size_t)((bb * NH + hh) * DH + d)) * SEQ + s] = f2bf(v);
            }
          }
        }
      }
    }
  }
  grid_bar(bars + 1, nblk);

  // ---------------- P2: causal flash attention (r6 body) ----------------
  {
    unsigned short* Ks = smem;           // [128][64]
    unsigned short* Vs = smem + 8192;    // [64][128]
    unsigned short* Ps = smem + 16384;   // [8][16*136]
    const int bx = bid & 7;
    const int h = (bid >> 3) & 15;
    const int b = bid >> 7;

    const int ksr1 = t >> 3;
    const int ksr2 = (t + 512) >> 3;
    const int koff1 = (b * SEQ + ksr1) * DM + h * 64 + (((t & 7) ^ (ksr1 & 7)) * 8);
    const int koff2 = (b * SEQ + ksr2) * DM + h * 64 + (((t & 7) ^ (ksr2 & 7)) * 8);
    const int vsr1 = t >> 4;
    const int vsr2 = (t + 512) >> 4;
    const int voff1 = ((b * NH + h) * DH + vsr1) * SEQ + (((t & 15) ^ (vsr1 & 15)) * 8);
    const int voff2 = ((b * NH + h) * DH + vsr2) * SEQ + (((t & 15) ^ (vsr2 & 15)) * 8);
    unsigned short* Pw = Ps + wave * 2176;
    const int swz8 = l16 & 7;

#pragma unroll 1
    for (int pass = 0; pass < 2; ++pass) {
      const int qt = (pass == 0) ? bx : 15 - bx;
      const int qtile = qt * 128;
      const int row_lo = qtile + wave * 16;
      const int row_hi = row_lo + 15;

      const unsigned short* Qrow =
          qb + ((size_t)(b * SEQ + row_lo + l16)) * DM + h * 64;
      const short8 qf0 = *(const short8*)(Qrow + quad * 8);
      const short8 qf1 = *(const short8*)(Qrow + 32 + quad * 8);

      f32x4 o_acc[4];
#pragma unroll
      for (int nb = 0; nb < 4; ++nb) o_acc[nb] = {0.0f, 0.0f, 0.0f, 0.0f};
      float l_r[4] = {0.0f, 0.0f, 0.0f, 0.0f};

      const int ktiles = qt + 1;
      for (int kt = 0; kt < ktiles; ++kt) {
        const int kbase = kt * 128;
        __syncthreads();
        gld_lds16(kb + koff1 + (size_t)kbase * DM, Ks + t * 8);
        gld_lds16(kb + koff2 + (size_t)kbase * DM, Ks + (t + 512) * 8);
        gld_lds16(vtb + voff1 + kbase, Vs + t * 8);
        gld_lds16(vtb + voff2 + kbase, Vs + (t + 512) * 8);
        __syncthreads();

        if (kbase <= row_hi) {
          f32x4 s_acc[8];
#pragma unroll
          for (int nb = 0; nb < 8; ++nb) {
            s_acc[nb] = {0.0f, 0.0f, 0.0f, 0.0f};
            const short8 kf0 = *(const short8*)(Ks + (nb * 16 + l16) * 64 + ((quad ^ swz8) * 8));
            const short8 kf1 = *(const short8*)(Ks + (nb * 16 + l16) * 64 + (((4 | quad) ^ swz8) * 8));
            s_acc[nb] = __builtin_amdgcn_mfma_f32_16x16x32_bf16(qf0, kf0, s_acc[nb], 0, 0, 0);
            s_acc[nb] = __builtin_amdgcn_mfma_f32_16x16x32_bf16(qf1, kf1, s_acc[nb], 0, 0, 0);
          }

          const bool need_mask = (kbase + 127 > row_lo);
#pragma unroll
          for (int r = 0; r < 4; ++r) {
            const int qr = row_lo + quad * 4 + r;
#pragma unroll
            for (int nb = 0; nb < 8; ++nb) {
              float p = __expf(s_acc[nb][r]);
              if (need_mask) p = ((kbase + nb * 16 + l16) <= qr) ? p : 0.0f;
              l_r[r] += p;
              const unsigned u = __builtin_bit_cast(unsigned, p);
              Pw[(quad * 4 + r) * 136 + nb * 16 + l16] =
                  (unsigned short)((u + 0x8000u) >> 16);
            }
          }

#pragma unroll
          for (int kk = 0; kk < 4; ++kk) {
            const short8 pf = *(const short8*)(Pw + l16 * 136 + kk * 32 + quad * 8);
#pragma unroll
            for (int nb = 0; nb < 4; ++nb) {
              const short8 vf = *(const short8*)(Vs + (nb * 16 + l16) * 128 +
                                                 (((kk * 4 + quad) ^ l16) * 8));
              o_acc[nb] = __builtin_amdgcn_mfma_f32_16x16x32_bf16(pf, vf, o_acc[nb], 0, 0, 0);
            }
          }
        }
      }

#pragma unroll
      for (int r = 0; r < 4; ++r) {
        float ls = l_r[r];
        ls += __shfl_xor(ls, 1);
        ls += __shfl_xor(ls, 2);
        ls += __shfl_xor(ls, 4);
        ls += __shfl_xor(ls, 8);
        const float inv_l = 1.0f / ls;
        const int qr = row_lo + quad * 4 + r;
#pragma unroll
        for (int nb = 0; nb < 4; ++nb)
          aob[((size_t)(b * SEQ + qr)) * DM + h * 64 + nb * 16 + l16] =
              f2bf(o_acc[nb][r] * inv_l);
      }
    }
  }
  grid_bar(bars + 2, nblk);

  // ---------------- P3: O-projection GEMM (1 tile, fp32 out) ----------------
  {
    unsigned short* As = smem;
    unsigned short* Bs = smem + 4096;
    const int wm = (wave >> 2) * 64;
    const int wn = (wave & 3) * 32;
    const int srow = t >> 2;
    const int sc = (t & 3) ^ ((srow >> 1) & 3);
    const int swz = (l16 >> 1) & 3;
    const int bm = (bid >> 3) * 128;
    const int bn = (bid & 7) * 128;
    const unsigned short* Ag = aob + (size_t)(bm + srow) * DM + sc * 8;
    const unsigned short* Bg = wob + (size_t)(bn + srow) * DM + sc * 8;

    f32x4 acc[4][2];
#pragma unroll
    for (int i = 0; i < 4; ++i)
#pragma unroll
      for (int j = 0; j < 2; ++j) acc[i][j] = {0.0f, 0.0f, 0.0f, 0.0f};

    for (int k0 = 0; k0 < DM; k0 += 32) {
      __syncthreads();
      gld_lds16(Ag + k0, As + t * 8);
      gld_lds16(Bg + k0, Bs + t * 8);
      __syncthreads();
      short8 af[4], bfr[2];
#pragma unroll
      for (int i = 0; i < 4; ++i)
        af[i] = *(const short8*)(As + (wm + i * 16 + l16) * 32 + ((quad ^ swz) * 8));
#pragma unroll
      for (int j = 0; j < 2; ++j)
        bfr[j] = *(const short8*)(Bs + (wn + j * 16 + l16) * 32 + ((quad ^ swz) * 8));
#pragma unroll
      for (int i = 0; i < 4; ++i)
#pragma unroll
        for (int j = 0; j < 2; ++j)
          acc[i][j] = __builtin_amdgcn_mfma_f32_16x16x32_bf16(af[i], bfr[j], acc[i][j], 0, 0, 0);
    }

#pragma unroll
    for (int i = 0; i < 4; ++i)
#pragma unroll
      for (int j = 0; j < 2; ++j)
#pragma unroll
        for (int r = 0; r < 4; ++r) {
          const int m = bm + wm + i * 16 + quad * 4 + r;
          const int n = bn + wn + j * 16 + l16;
          dout[(size_t)m * DM + n] = acc[i][j][r];
        }
  }
}

// ==================== fallback: round-6 four-kernel pipeline ====================
__global__ __launch_bounds__(256) void cast_all_kernel(const float* __restrict__ x,
                                                       const float* __restrict__ wq,
                                                       const float* __restrict__ wk,
                                                       const float* __restrict__ wv,
                                                       const float* __restrict__ wo,
                                                       unsigned short* __restrict__ xb,
                                                       unsigned short* __restrict__ wqkvb,
                                                       unsigned short* __restrict__ wob) {
  const int bid = blockIdx.x;
  const float* in;
  unsigned short* out;
  int i;
  if (bid < 8192) {
    in = x; out = xb; i = bid * 256 + threadIdx.x;
  } else {
    const int w = (bid - 8192) >> 10;
    i = ((bid - 8192) & 1023) * 256 + threadIdx.x;
    in = (w == 0) ? wq : (w == 1) ? wk : (w == 2) ? wv : wo;
    out = (w < 3) ? (wqkvb + (size_t)w * 1048576) : wob;
  }
  const float4 v = ((const float4*)in)[i];
  ushort4 o;
  o.x = f2bf(v.x); o.y = f2bf(v.y); o.z = f2bf(v.z); o.w = f2bf(v.w);
  ((ushort4*)out)[i] = o;
}

__global__ __launch_bounds__(256, 4) void gemm_qkv(const unsigned short* __restrict__ A,
                                                   const unsigned short* __restrict__ W,
                                                   unsigned short* __restrict__ qb,
                                                   unsigned short* __restrict__ kb,
                                                   unsigned short* __restrict__ vtb) {
  __shared__ __align__(16) unsigned short As[128 * 32];
  __shared__ __align__(16) unsigned short Bs[128 * 32];
  const int t = threadIdx.x;
  const int lane = t & 63;
  const int wave = t >> 6;
  const int quad = lane >> 4;
  const int l16 = lane & 15;
  const int wm = (wave >> 1) * 64;
  const int wn = (wave & 1) * 64;
  const int bm = blockIdx.y * 128;
  const int bn = blockIdx.x * 128;
  const int sel = bn >> 10;
  const int bnl = bn & 1023;

  f32x4 acc[4][4];
#pragma unroll
  for (int i = 0; i < 4; ++i)
#pragma unroll
    for (int j = 0; j < 4; ++j) acc[i][j] = {0.0f, 0.0f, 0.0f, 0.0f};

  const int srow = t >> 2;
  const int sc = (t & 3) ^ ((srow >> 1) & 3);
  const unsigned short* Ag1 = A + (size_t)(bm + srow) * DM + sc * 8;
  const unsigned short* Ag2 = A + (size_t)(bm + srow + 64) * DM + sc * 8;
  const unsigned short* Bg1 = W + (size_t)(bn + srow) * DM + sc * 8;
  const unsigned short* Bg2 = W + (size_t)(bn + srow + 64) * DM + sc * 8;
  const int swz = (l16 >> 1) & 3;

  for (int k0 = 0; k0 < DM; k0 += 32) {
    __syncthreads();
    gld_lds16(Ag1 + k0, As + t * 8);
    gld_lds16(Ag2 + k0, As + t * 8 + 2048);
    gld_lds16(Bg1 + k0, Bs + t * 8);
    gld_lds16(Bg2 + k0, Bs + t * 8 + 2048);
    __syncthreads();
    short8 af[4], bfr[4];
#pragma unroll
    for (int i = 0; i < 4; ++i)
      af[i] = *(const short8*)(As + (wm + i * 16 + l16) * 32 + ((quad ^ swz) * 8));
#pragma unroll
    for (int j = 0; j < 4; ++j)
      bfr[j] = *(const short8*)(Bs + (wn + j * 16 + l16) * 32 + ((quad ^ swz) * 8));
#pragma unroll
    for (int i = 0; i < 4; ++i)
#pragma unroll
      for (int j = 0; j < 4; ++j)
        acc[i][j] = __builtin_amdgcn_mfma_f32_16x16x32_bf16(af[i], bfr[j], acc[i][j], 0, 0, 0);
  }

#pragma unroll
  for (int i = 0; i < 4; ++i) {
#pragma unroll
    for (int j = 0; j < 4; ++j) {
#pragma unroll
      for (int r = 0; r < 4; ++r) {
        const int m = bm + wm + i * 16 + quad * 4 + r;
        const int n = bnl + wn + j * 16 + l16;
        const float v = acc[i][j][r];
        if (sel == 0) {
          qb[(size_t)m * DM + n] = f2bf(v * 0.125f);
        } else if (sel == 1) {
          kb[(size_t)m * DM + n] = f2bf(v);
        } else {
          const int bb = m >> 11, s = m & 2047;
          const int h = n >> 6, d = n & 63;
          vtb[((size_t)((bb * NH + h) * DH + d)) * SEQ + s] = f2bf(v);
        }
      }
    }
  }
}

__global__ __launch_bounds__(256, 4) void gemm_o(const unsigned short* __restrict__ A,
                                                 const unsigned short* __restrict__ B,
                                                 float* __restrict__ C) {
  __shared__ __align__(16) unsigned short As[128 * 32];
  __shared__ __align__(16) unsigned short Bs[128 * 32];
  const int t = threadIdx.x;
  const int lane = t & 63;
  const int wave = t >> 6;
  const int quad = lane >> 4;
  const int l16 = lane & 15;
  const int wm = (wave >> 1) * 64;
  const int wn = (wave & 1) * 64;
  const int bm = blockIdx.y * 128;
  const int bn = blockIdx.x * 128;

  f32x4 acc[4][4];
#pragma unroll
  for (int i = 0; i < 4; ++i)
#pragma unroll
    for (int j = 0; j < 4; ++j) acc[i][j] = {0.0f, 0.0f, 0.0f, 0.0f};

  const int srow = t >> 2;
  const int sc = (t & 3) ^ ((srow >> 1) & 3);
  const unsigned short* Ag1 = A + (size_t)(bm + srow) * DM + sc * 8;
  const unsigned short* Ag2 = A + (size_t)(bm + srow + 64) * DM + sc * 8;
  const unsigned short* Bg1 = B + (size_t)(bn + srow) * DM + sc * 8;
  const unsigned short* Bg2 = B + (size_t)(bn + srow + 64) * DM + sc * 8;
  const int swz = (l16 >> 1) & 3;

  for (int k0 = 0; k0 < DM; k0 += 32) {
    __syncthreads();
    gld_lds16(Ag1 + k0, As + t * 8);
    gld_lds16(Ag2 + k0, As + t * 8 + 2048);
    gld_lds16(Bg1 + k0, Bs + t * 8);
    gld_lds16(Bg2 + k0, Bs + t * 8 + 2048);
    __syncthreads();
    short8 af[4], bfr[4];
#pragma unroll
    for (int i = 0; i < 4; ++i)
      af[i] = *(const short8*)(As + (wm + i * 16 + l16) * 32 + ((quad ^ swz) * 8));
#pragma unroll
    for (int j = 0; j < 4; ++j)
      bfr[j] = *(const short8*)(Bs + (wn + j * 16 + l16) * 32 + ((quad ^ swz) * 8));
#pragma unroll
    for (int i = 0; i < 4; ++i)
#pragma unroll
      for (int j = 0; j < 4; ++j)
        acc[i][j] = __builtin_amdgcn_mfma_f32_16x16x32_bf16(af[i], bfr[j], acc[i][j], 0, 0, 0);
  }

#pragma unroll
  for (int i = 0; i < 4; ++i)
#pragma unroll
    for (int j = 0; j < 4; ++j)
#pragma unroll
      for (int r = 0; r < 4; ++r) {
        const int m = bm + wm + i * 16 + quad * 4 + r;
        const int n = bn + wn + j * 16 + l16;
        C[(size_t)m * DM + n] = acc[i][j][r];
      }
}

__global__ __launch_bounds__(512) void attn_kernel(const unsigned short* __restrict__ Q,
                                                   const unsigned short* __restrict__ K,
                                                   const unsigned short* __restrict__ Vt,
                                                   unsigned short* __restrict__ O) {
  __shared__ __align__(16) unsigned short Ks[128 * 64];
  __shared__ __align__(16) unsigned short Vs[64 * 128];
  __shared__ __align__(16) unsigned short Ps[8][16 * 136];
  const int t = threadIdx.x;
  const int lane = t & 63;
  const int wave = t >> 6;
  const int quad = lane >> 4;
  const int l16 = lane & 15;
  const int h = blockIdx.y;
  const int b = blockIdx.z;

  const int ksr1 = t >> 3;
  const int ksr2 = (t + 512) >> 3;
  const int koff1 = (b * SEQ + ksr1) * DM + h * 64 + (((t & 7) ^ (ksr1 & 7)) * 8);
  const int koff2 = (b * SEQ + ksr2) * DM + h * 64 + (((t & 7) ^ (ksr2 & 7)) * 8);
  const int vsr1 = t >> 4;
  const int vsr2 = (t + 512) >> 4;
  const int voff1 = ((b * NH + h) * DH + vsr1) * SEQ + (((t & 15) ^ (vsr1 & 15)) * 8);
  const int voff2 = ((b * NH + h) * DH + vsr2) * SEQ + (((t & 15) ^ (vsr2 & 15)) * 8);
  unsigned short* Pw = &Ps[wave][0];
  const int swz8 = l16 & 7;

#pragma unroll 1
  for (int pass = 0; pass < 2; ++pass) {
    const int qt = (pass == 0) ? (int)blockIdx.x : 15 - (int)blockIdx.x;
    const int qtile = qt * 128;
    const int row_lo = qtile + wave * 16;
    const int row_hi = row_lo + 15;

    const unsigned short* Qrow =
        Q + ((size_t)(b * SEQ + row_lo + l16)) * DM + h * 64;
    const short8 qf0 = *(const short8*)(Qrow + quad * 8);
    const short8 qf1 = *(const short8*)(Qrow + 32 + quad * 8);

    f32x4 o_acc[4];
#pragma unroll
    for (int nb = 0; nb < 4; ++nb) o_acc[nb] = {0.0f, 0.0f, 0.0f, 0.0f};
    float l_r[4] = {0.0f, 0.0f, 0.0f, 0.0f};

    const int ktiles = qt + 1;
    for (int kt = 0; kt < ktiles; ++kt) {
      const int kbase = kt * 128;
      __syncthreads();
      gld_lds16(K + koff1 + (size_t)kbase * DM, Ks + t * 8);
      gld_lds16(K + koff2 + (size_t)kbase * DM, Ks + (t + 512) * 8);
      gld_lds16(Vt + voff1 + kbase, Vs + t * 8);
      gld_lds16(Vt + voff2 + kbase, Vs + (t + 512) * 8);
      __syncthreads();

      if (kbase <= row_hi) {
        f32x4 s_acc[8];
#pragma unroll
        for (int nb = 0; nb < 8; ++nb) {
          s_acc[nb] = {0.0f, 0.0f, 0.0f, 0.0f};
          const short8 kf0 = *(const short8*)(Ks + (nb * 16 + l16) * 64 + ((quad ^ swz8) * 8));
          const short8 kf1 = *(const short8*)(Ks + (nb * 16 + l16) * 64 + (((4 | quad) ^ swz8) * 8));
          s_acc[nb] = __builtin_amdgcn_mfma_f32_16x16x32_bf16(qf0, kf0, s_acc[nb], 0, 0, 0);
          s_acc[nb] = __builtin_amdgcn_mfma_f32_16x16x32_bf16(qf1, kf1, s_acc[nb], 0, 0, 0);
        }

        const bool need_mask = (kbase + 127 > row_lo);
#pragma unroll
        for (int r = 0; r < 4; ++r) {
          const int qr = row_lo + quad * 4 + r;
#pragma unroll
          for (int nb = 0; nb < 8; ++nb) {
            float p = __expf(s_acc[nb][r]);
            if (need_mask) p = ((kbase + nb * 16 + l16) <= qr) ? p : 0.0f;
            l_r[r] += p;
            const unsigned u = __builtin_bit_cast(unsigned, p);
            Pw[(quad * 4 + r) * 136 + nb * 16 + l16] =
                (unsigned short)((u + 0x8000u) >> 16);
          }
        }

#pragma unroll
        for (int kk = 0; kk < 4; ++kk) {
          const short8 pf = *(const short8*)(Pw + l16 * 136 + kk * 32 + quad * 8);
#pragma unroll
          for (int nb = 0; nb < 4; ++nb) {
            const short8 vf = *(const short8*)(Vs + (nb * 16 + l16) * 128 +
                                               (((kk * 4 + quad) ^ l16) * 8));
            o_acc[nb] = __builtin_amdgcn_mfma_f32_16x16x32_bf16(pf, vf, o_acc[nb], 0, 0, 0);
          }
        }
      }
    }

#pragma unroll
    for (int r = 0; r < 4; ++r) {
      float ls = l_r[r];
      ls += __shfl_xor(ls, 1);
      ls += __shfl_xor(ls, 2);
      ls += __shfl_xor(ls, 4);
      ls += __shfl_xor(ls, 8);
      const float inv_l = 1.0f / ls;
      const int qr = row_lo + quad * 4 + r;
#pragma unroll
      for (int nb = 0; nb < 4; ++nb)
        O[((size_t)(b * SEQ + qr)) * DM + h * 64 + nb * 16 + l16] =
            f2bf(o_acc[nb][r] * inv_l);
    }
  }
}

extern "C" void kernel_launch(void* const* d_in, const int* in_sizes, int n_in,
                              void* d_out, int out_size, void* d_ws, size_t ws_size,
                              hipStream_t stream) {
  const float* x  = (const float*)d_in[0];
  const float* wq = (const float*)d_in[1];
  const float* wk = (const float*)d_in[2];
  const float* wv = (const float*)d_in[3];
  const float* wo = (const float*)d_in[4];

  char* ws = (char*)d_ws;
  unsigned short* xb    = (unsigned short*)(ws);              // 16 MiB
  unsigned short* wqkvb = (unsigned short*)(ws + 16777216);   // 6 MiB
  unsigned short* wob   = (unsigned short*)(ws + 23068672);   // 2 MiB
  unsigned short* qb    = (unsigned short*)(ws + 25165824);   // 16 MiB (pre-scaled)
  unsigned short* kb    = (unsigned short*)(ws + 41943040);   // 16 MiB
  unsigned short* vtb   = (unsigned short*)(ws + 58720256);   // 16 MiB [B,NH,DH,SEQ]
  unsigned short* aob   = (unsigned short*)(ws + 75497472);   // 16 MiB (ends 92,274,688)

  if (ws_size >= 92274688ull + 256ull) {
    unsigned* bars = (unsigned*)(ws + 92274688);
    hipMemsetAsync(bars, 0, 256, stream);
    fused_mha<<<512, 512, 0, stream>>>(x, wq, wk, wv, wo, xb, wqkvb, wob,
                                       qb, kb, vtb, aob, (float*)d_out, bars);
  } else {
    cast_all_kernel<<<12288, 256, 0, stream>>>(x, wq, wk, wv, wo, xb, wqkvb, wob);
    gemm_qkv<<<dim3(24, 64), 256, 0, stream>>>(xb, wqkvb, qb, kb, vtb);
    attn_kernel<<<dim3(8, NH, 4), 512, 0, stream>>>(qb, kb, vtb, aob);
    gemm_o<<<dim3(8, 64), 256, 0, stream>>>(aob, wob, (float*)d_out);
  }
}